// Round 1
// baseline (147.097 us; speedup 1.0000x reference)
//
#include <hip/hip_runtime.h>
#include <hip/hip_fp16.h>

#define RES 0.1f

constexpr int B_  = 512;
constexpr int N_  = 8192;        // points per batch
constexpr int W_  = 200;
constexpr int MAP = 200 * 200;   // 40000 cells
constexpr long long TOTAL = (long long)B_ * N_;   // 4,194,304 (2^22)

constexpr int TPB = 1024;        // 16 waves; fp16 map (80,000 B) -> 2 blocks/CU

__global__ __launch_bounds__(TPB, 8) void collision_fused(
    const float* __restrict__ opState,
    const float* __restrict__ envs,
    float* __restrict__ out)
{
    __shared__ __half smap[MAP];         // 80,000 B — two blocks co-resident per CU
    __shared__ float  sacc[TPB / 64];

    const int b   = blockIdx.x;          // one batch per block
    const int tid = threadIdx.x;

    // ---- prefetch this block's 8 points (4 x float4, fully coalesced) ----
    const float4* p4 = (const float4*)(opState + (long long)b * N_ * 2);
    float4 pp0 = p4[tid];
    float4 pp1 = p4[tid + TPB];
    float4 pp2 = p4[tid + 2 * TPB];
    float4 pp3 = p4[tid + 3 * TPB];

    // ---- stage map -> LDS as fp16 (coalesced float4 reads, ds_write_b64) ----
    const float4* m4 = (const float4*)(envs + (long long)b * MAP);
    #pragma unroll
    for (int k = 0; k < 9; ++k) {        // 9*1024 = 9216 of 10000 vec4
        const int j = tid + k * TPB;
        float4 v = m4[j];
        __half2 h01 = __floats2half2_rn(v.x, v.y);
        __half2 h23 = __floats2half2_rn(v.z, v.w);
        *(__half2*)(smap + 4 * j)     = h01;
        *(__half2*)(smap + 4 * j + 2) = h23;
    }
    if (tid < MAP / 4 - 9 * TPB) {       // 784-element tail
        const int j = tid + 9 * TPB;
        float4 v = m4[j];
        __half2 h01 = __floats2half2_rn(v.x, v.y);
        __half2 h23 = __floats2half2_rn(v.z, v.w);
        *(__half2*)(smap + 4 * j)     = h01;
        *(__half2*)(smap + 4 * j + 2) = h23;
    }
    __syncthreads();

    float acc = 0.0f;
    auto point = [&](float x, float y) {
        bool oor = (x < -9.9f) | (x > 9.9f) | (y < -9.9f) | (y > 9.9f);
        float px = fminf(fmaxf(x, -9.9f), 9.9f);
        float py = fminf(fmaxf(y, -9.9f), 9.9f);
        float pmx = px - 0.5f * RES;
        float pmy = py - 0.5f * RES;
        int ix = (int)floorf((pmx + 10.0f) * 10.0f);
        int iy = (int)floorf((pmy + 10.0f) * 10.0f);
        float ipx = ((float)ix + 0.5f) * RES - 10.0f;
        float ipy = ((float)iy + 0.5f) * RES - 10.0f;
        float dx = (px - ipx) * 10.0f;
        float dy = (py - ipy) * 10.0f;
        int base = ix * W_ + iy;
        float v00 = __half2float(smap[base]);
        float v01 = __half2float(smap[base + 1]);
        float v10 = __half2float(smap[base + W_]);
        float v11 = __half2float(smap[base + W_ + 1]);
        float vx0 = (1.0f - dx) * v00 + dx * v10;
        float vx1 = (1.0f - dx) * v01 + dx * v11;
        float v   = (1.0f - dy) * vx0 + dy * vx1;
        float dists = oor ? -1.0f : v;
        float viod  = 10.0f * (0.3f - dists);
        float r     = fmaxf(viod, 0.0f);
        acc += r * r;
    };
    point(pp0.x, pp0.y); point(pp0.z, pp0.w);
    point(pp1.x, pp1.y); point(pp1.z, pp1.w);
    point(pp2.x, pp2.y); point(pp2.z, pp2.w);
    point(pp3.x, pp3.y); point(pp3.z, pp3.w);

    // ---- block reduction: wave64 shuffle, then cross-wave via LDS ----
    #pragma unroll
    for (int off = 32; off > 0; off >>= 1)
        acc += __shfl_down(acc, off, 64);

    const int lane = tid & 63;
    const int wid  = tid >> 6;
    if (lane == 0) sacc[wid] = acc;
    __syncthreads();

    if (tid == 0) {
        float s = 0.0f;
        #pragma unroll
        for (int w = 0; w < TPB / 64; ++w) s += sacc[w];
        // 1/2^22 is exact; per-block scaling == global scaling bit-wise per op
        atomicAdd(out, s * (1.0f / (float)TOTAL));
    }
}

extern "C" void kernel_launch(void* const* d_in, const int* in_sizes, int n_in,
                              void* d_out, int out_size, void* d_ws, size_t ws_size,
                              hipStream_t stream) {
    const float* opState = (const float*)d_in[0];   // (512, 8192, 2) f32
    const float* envs    = (const float*)d_in[1];   // (512, 1, 200, 200) f32
    float* out = (float*)d_out;                     // scalar f32

    hipMemsetAsync(out, 0, sizeof(float), stream);  // capturable; stream-ordered
    collision_fused<<<B_, TPB, 0, stream>>>(opState, envs, out);
}